// Round 1
// baseline (71.016 us; speedup 1.0000x reference)
//
#include <hip/hip_runtime.h>
#include <hip/hip_bf16.h>

// PseudoTripletLoss on MI355X (gfx950)
// loss = sum_{i<j} [ same(i,j) ? relu(1 - cos_ij) : relu(cos_ij - 0.1) ] / (n(n-1))
//
// K1: row-normalize fp32 embeddings -> bf16 `en` in d_ws (one wave per row)
// K2: upper-triangle 128x128 tiles: sim tile via mfma_f32_16x16x32_bf16,
//     fused hinge-loss epilogue + per-block reduction -> partials in d_ws.
//     Operands read directly from global (en is 2 MB, L2-resident).
// K3: deterministic single-block reduction of partials -> d_out[0]
//
// Robustness notes:
//  - MFMA k-lane-mapping cancels (A and B loaded with identical assumed map).
//  - sim and pair_loss are symmetric => any C/D transpose is value-neutral
//    under the uniform strict i<j mask.

typedef __attribute__((ext_vector_type(8))) short short8;
typedef __attribute__((ext_vector_type(4))) float f32x4;

#define DIM 128
#define MARGIN 0.1f

static __device__ __forceinline__ unsigned short f2bf(float f) {
    unsigned int u = __builtin_bit_cast(unsigned int, f);
    u += 0x7FFFu + ((u >> 16) & 1u);   // round-to-nearest-even
    return (unsigned short)(u >> 16);
}

// ---------------- K1: normalize rows, write packed bf16 ----------------
__global__ void __launch_bounds__(256) norm_bf16_kernel(const float* __restrict__ e,
                                                        unsigned int* __restrict__ en_packed) {
    const int row  = blockIdx.x * 4 + (threadIdx.x >> 6);  // one wave per row
    const int lane = threadIdx.x & 63;
    const float2 v = *reinterpret_cast<const float2*>(e + row * DIM + lane * 2);
    float s = v.x * v.x + v.y * v.y;
    #pragma unroll
    for (int off = 32; off; off >>= 1) s += __shfl_xor(s, off, 64);
    const float scale = 1.0f / fmaxf(sqrtf(s), 1e-8f);
    const unsigned int lo = f2bf(v.x * scale);
    const unsigned int hi = f2bf(v.y * scale);
    en_packed[row * (DIM / 2) + lane] = (hi << 16) | lo;
}

// ---------------- K2: tile GEMM + fused hinge loss ----------------
__global__ void __launch_bounds__(256) tri_loss_kernel(const short* __restrict__ en,
                                                       const int* __restrict__ labels,
                                                       float* __restrict__ partials) {
    const int bj  = blockIdx.x;            // col tile
    const int bi  = blockIdx.y;            // row tile
    const int bid = bi * gridDim.x + bj;
    if (bj < bi) {                          // lower-triangle blocks: no work
        if (threadIdx.x == 0) partials[bid] = 0.0f;
        return;
    }
    const int lane = threadIdx.x & 63;
    const int wid  = threadIdx.x >> 6;      // 4 waves: 2x2 quadrants of 64x64
    const int r0   = bi * 128 + (wid >> 1) * 64;
    const int c0   = bj * 128 + (wid & 1) * 64;
    const int lm   = lane & 15;
    const int lk   = (lane >> 4) * 8;       // assumed contiguous-8 k map (A==B => cancels)

    f32x4 acc[4][4] = {};
    #pragma unroll
    for (int ks = 0; ks < 4; ++ks) {        // K = 128 in 4 steps of 32
        const int kb = ks * 32 + lk;
        short8 a[4], b[4];
        #pragma unroll
        for (int m = 0; m < 4; ++m)
            a[m] = *reinterpret_cast<const short8*>(en + (r0 + m * 16 + lm) * DIM + kb);
        #pragma unroll
        for (int n = 0; n < 4; ++n)
            b[n] = *reinterpret_cast<const short8*>(en + (c0 + n * 16 + lm) * DIM + kb);
        #pragma unroll
        for (int m = 0; m < 4; ++m)
            #pragma unroll
            for (int n = 0; n < 4; ++n)
                acc[m][n] = __builtin_amdgcn_mfma_f32_16x16x32_bf16(a[m], b[n], acc[m][n], 0, 0, 0);
    }

    // Epilogue: C/D map (verified): col = lane&15, row = (lane>>4)*4 + reg
    const int rb = (lane >> 4) * 4;
    float lsum = 0.0f;
    int labj[4];
    #pragma unroll
    for (int n = 0; n < 4; ++n) labj[n] = labels[c0 + n * 16 + lm];
    #pragma unroll
    for (int m = 0; m < 4; ++m) {
        #pragma unroll
        for (int r = 0; r < 4; ++r) {
            const int i  = r0 + m * 16 + rb + r;
            const int li = labels[i];
            #pragma unroll
            for (int n = 0; n < 4; ++n) {
                const int j   = c0 + n * 16 + lm;
                const float sim = acc[m][n][r];
                const float t   = (li == labj[n]) ? (1.0f - sim) : (sim - MARGIN);
                if (i < j) lsum += fmaxf(t, 0.0f);
            }
        }
    }

    #pragma unroll
    for (int off = 32; off; off >>= 1) lsum += __shfl_down(lsum, off, 64);
    __shared__ float wsum[4];
    if (lane == 0) wsum[wid] = lsum;
    __syncthreads();
    if (threadIdx.x == 0) partials[bid] = wsum[0] + wsum[1] + wsum[2] + wsum[3];
}

// ---------------- K3: final deterministic reduce ----------------
__global__ void __launch_bounds__(256) final_reduce_kernel(const float* __restrict__ partials,
                                                           float* __restrict__ out,
                                                           int n, float inv_denom) {
    float s = 0.0f;
    for (int i = threadIdx.x; i < n; i += 256) s += partials[i];
    #pragma unroll
    for (int off = 32; off; off >>= 1) s += __shfl_xor(s, off, 64);
    __shared__ float wsum[4];
    if ((threadIdx.x & 63) == 0) wsum[threadIdx.x >> 6] = s;
    __syncthreads();
    if (threadIdx.x == 0) out[0] = (wsum[0] + wsum[1] + wsum[2] + wsum[3]) * inv_denom;
}

extern "C" void kernel_launch(void* const* d_in, const int* in_sizes, int n_in,
                              void* d_out, int out_size, void* d_ws, size_t ws_size,
                              hipStream_t stream) {
    const float* emb    = (const float*)d_in[0];
    const int*   labels = (const int*)d_in[1];
    float*       out    = (float*)d_out;

    const int n  = in_sizes[1];      // 8192
    const int nt = n / 128;          // 64 tiles per dim

    unsigned int* en_packed = (unsigned int*)d_ws;                 // n*DIM bf16 = 2 MB
    short*        en        = (short*)d_ws;
    float*        partials  = (float*)((char*)d_ws + (size_t)n * DIM * 2);  // nt*nt floats

    norm_bf16_kernel<<<n / 4, 256, 0, stream>>>(emb, en_packed);

    dim3 grid(nt, nt);
    tri_loss_kernel<<<grid, 256, 0, stream>>>(en, labels, partials);

    const float inv_denom = (float)(1.0 / ((double)n * (double)(n - 1)));
    final_reduce_kernel<<<1, 256, 0, stream>>>(partials, out, nt * nt, inv_denom);
}

// Round 2
// 56.375 us; speedup vs baseline: 1.2597x; 1.2597x over previous
//
#include <hip/hip_runtime.h>
#include <hip/hip_bf16.h>

// PseudoTripletLoss on MI355X (gfx950)
// loss = sum_{i<j} [ same(i,j) ? relu(1 - cos_ij) : relu(cos_ij - 0.1) ] / (n(n-1))
//
// K1: row-normalize fp32 embeddings -> bf16 `en` in d_ws (one wave per row)
// K2: triangular grid (2080 blocks), one 128x128 sim tile per block via
//     mfma_f32_16x16x32_bf16. All K=128 operands hoisted to registers
//     (32x 16B loads in flight) before the MFMA chain -> hides L2 latency.
//     Fused hinge-loss epilogue + per-block reduction -> partials.
// K3: deterministic single-block reduction of partials -> d_out[0]
//
// Robustness notes:
//  - MFMA k-lane-mapping cancels (A and B loaded with identical assumed map).
//  - sim and pair_loss are symmetric => any C/D transpose is value-neutral
//    under the uniform strict i<j mask.

typedef __attribute__((ext_vector_type(8))) short short8;
typedef __attribute__((ext_vector_type(4))) float f32x4;

#define DIM 128
#define MARGIN 0.1f

static __device__ __forceinline__ unsigned short f2bf(float f) {
    unsigned int u = __builtin_bit_cast(unsigned int, f);
    u += 0x7FFFu + ((u >> 16) & 1u);   // round-to-nearest-even
    return (unsigned short)(u >> 16);
}

// ---------------- K1: normalize rows, write packed bf16 ----------------
__global__ void __launch_bounds__(256) norm_bf16_kernel(const float* __restrict__ e,
                                                        unsigned int* __restrict__ en_packed) {
    const int row  = blockIdx.x * 4 + (threadIdx.x >> 6);  // one wave per row
    const int lane = threadIdx.x & 63;
    const float2 v = *reinterpret_cast<const float2*>(e + row * DIM + lane * 2);
    float s = v.x * v.x + v.y * v.y;
    #pragma unroll
    for (int off = 32; off; off >>= 1) s += __shfl_xor(s, off, 64);
    const float scale = 1.0f / fmaxf(sqrtf(s), 1e-8f);
    const unsigned int lo = f2bf(v.x * scale);
    const unsigned int hi = f2bf(v.y * scale);
    en_packed[row * (DIM / 2) + lane] = (hi << 16) | lo;
}

// ---------------- K2: triangular tile GEMM + fused hinge loss ----------------
__global__ void __launch_bounds__(256) tri_loss_kernel(const short* __restrict__ en,
                                                       const int* __restrict__ labels,
                                                       float* __restrict__ partials,
                                                       int nt) {
    // decode linear block id -> upper-triangle (bi, bj), bj >= bi
    const int t = blockIdx.x;
    // off(r) = r*nt - r*(r-1)/2 ; r ~= (2nt+1 - sqrt((2nt+1)^2 - 8t)) / 2
    const float w = (float)(2 * nt + 1);
    int bi = (int)((w - sqrtf(w * w - 8.0f * (float)t)) * 0.5f);
    #pragma unroll 1
    while (bi > 0 && (bi * nt - (bi * (bi - 1)) / 2) > t) --bi;
    #pragma unroll 1
    while (((bi + 1) * nt - ((bi + 1) * bi) / 2) <= t) ++bi;
    const int bj = bi + (t - (bi * nt - (bi * (bi - 1)) / 2));

    const int lane = threadIdx.x & 63;
    const int wid  = threadIdx.x >> 6;      // 4 waves: 2x2 quadrants of 64x64
    const int r0   = bi * 128 + (wid >> 1) * 64;
    const int c0   = bj * 128 + (wid & 1) * 64;
    const int lm   = lane & 15;
    const int lk   = (lane >> 4) * 8;       // assumed contiguous-8 k map (A==B => cancels)

    // Hoist ALL operands for K=128: 16 + 16 short8 (32 loads in flight)
    short8 a[4][4], b[4][4];                 // [m or n][ks]
    #pragma unroll
    for (int m = 0; m < 4; ++m) {
        const short* pa = en + (r0 + m * 16 + lm) * DIM + lk;
        #pragma unroll
        for (int ks = 0; ks < 4; ++ks)
            a[m][ks] = *reinterpret_cast<const short8*>(pa + ks * 32);
    }
    #pragma unroll
    for (int n = 0; n < 4; ++n) {
        const short* pb = en + (c0 + n * 16 + lm) * DIM + lk;
        #pragma unroll
        for (int ks = 0; ks < 4; ++ks)
            b[n][ks] = *reinterpret_cast<const short8*>(pb + ks * 32);
    }

    f32x4 acc[4][4] = {};
    #pragma unroll
    for (int ks = 0; ks < 4; ++ks)
        #pragma unroll
        for (int m = 0; m < 4; ++m)
            #pragma unroll
            for (int n = 0; n < 4; ++n)
                acc[m][n] = __builtin_amdgcn_mfma_f32_16x16x32_bf16(a[m][ks], b[n][ks], acc[m][n], 0, 0, 0);

    // Epilogue: C/D map: col = lane&15, row = (lane>>4)*4 + reg
    const int rb = (lane >> 4) * 4;
    float lsum = 0.0f;
    int labj[4];
    #pragma unroll
    for (int n = 0; n < 4; ++n) labj[n] = labels[c0 + n * 16 + lm];
    #pragma unroll
    for (int m = 0; m < 4; ++m) {
        #pragma unroll
        for (int r = 0; r < 4; ++r) {
            const int i  = r0 + m * 16 + rb + r;
            const int li = labels[i];
            #pragma unroll
            for (int n = 0; n < 4; ++n) {
                const int j   = c0 + n * 16 + lm;
                const float sim = acc[m][n][r];
                const float t2  = (li == labj[n]) ? (1.0f - sim) : (sim - MARGIN);
                if (i < j) lsum += fmaxf(t2, 0.0f);
            }
        }
    }

    #pragma unroll
    for (int off = 32; off; off >>= 1) lsum += __shfl_down(lsum, off, 64);
    __shared__ float wsum[4];
    if (lane == 0) wsum[wid] = lsum;
    __syncthreads();
    if (threadIdx.x == 0) partials[blockIdx.x] = wsum[0] + wsum[1] + wsum[2] + wsum[3];
}

// ---------------- K3: final deterministic reduce ----------------
__global__ void __launch_bounds__(256) final_reduce_kernel(const float* __restrict__ partials,
                                                           float* __restrict__ out,
                                                           int n, float inv_denom) {
    float s = 0.0f;
    for (int i = threadIdx.x; i < n; i += 256) s += partials[i];
    #pragma unroll
    for (int off = 32; off; off >>= 1) s += __shfl_xor(s, off, 64);
    __shared__ float wsum[4];
    if ((threadIdx.x & 63) == 0) wsum[threadIdx.x >> 6] = s;
    __syncthreads();
    if (threadIdx.x == 0) out[0] = (wsum[0] + wsum[1] + wsum[2] + wsum[3]) * inv_denom;
}

extern "C" void kernel_launch(void* const* d_in, const int* in_sizes, int n_in,
                              void* d_out, int out_size, void* d_ws, size_t ws_size,
                              hipStream_t stream) {
    const float* emb    = (const float*)d_in[0];
    const int*   labels = (const int*)d_in[1];
    float*       out    = (float*)d_out;

    const int n  = in_sizes[1];      // 8192
    const int nt = n / 128;          // 64 tiles per dim
    const int ntri = nt * (nt + 1) / 2;   // 2080 upper-triangle tiles

    unsigned int* en_packed = (unsigned int*)d_ws;                 // n*DIM bf16 = 2 MB
    short*        en        = (short*)d_ws;
    float*        partials  = (float*)((char*)d_ws + (size_t)n * DIM * 2);  // ntri floats

    norm_bf16_kernel<<<n / 4, 256, 0, stream>>>(emb, en_packed);

    tri_loss_kernel<<<ntri, 256, 0, stream>>>(en, labels, partials, nt);

    const float inv_denom = (float)(1.0 / ((double)n * (double)(n - 1)));
    final_reduce_kernel<<<1, 256, 0, stream>>>(partials, out, ntri, inv_denom);
}

// Round 3
// 42.580 us; speedup vs baseline: 1.6678x; 1.3240x over previous
//
#include <hip/hip_runtime.h>
#include <hip/hip_bf16.h>

// PseudoTripletLoss on MI355X (gfx950)
// loss = sum_{i<j} [ same(i,j) ? relu(1 - cos_ij) : relu(cos_ij - 0.1) ] / (n(n-1))
//
// K1: row-normalize fp32 embeddings -> bf16 `en` in d_ws (one wave per row)
// K2: strip-chunked triangular GEMM: block = (row-strip bi, chunk of 4 col tiles).
//     A strip (128 rows x K=128) held in registers for the whole block.
//     B tiles double-buffered in LDS via global_load_lds (pre-swizzled source,
//     XOR-swizzled ds_read -> conflict-free), 2-phase pipeline (T3-lite).
//     Fused hinge-loss epilogue per tile -> per-block partial.
// K3: deterministic single-block reduction of partials -> d_out[0]

typedef __attribute__((ext_vector_type(8))) short short8;
typedef __attribute__((ext_vector_type(4))) float f32x4;

#define DIM 128
#define MARGIN 0.1f
#define CHUNK 4

typedef const void __attribute__((address_space(1)))* gas_ptr;
typedef void __attribute__((address_space(3)))* las_ptr;

static __device__ __forceinline__ void load16_to_lds(const void* g, void* l) {
    __builtin_amdgcn_global_load_lds((gas_ptr)g, (las_ptr)l, 16, 0, 0);
}

static __device__ __forceinline__ unsigned short f2bf(float f) {
    unsigned int u = __builtin_bit_cast(unsigned int, f);
    u += 0x7FFFu + ((u >> 16) & 1u);   // round-to-nearest-even
    return (unsigned short)(u >> 16);
}

// ---------------- K1: normalize rows, write packed bf16 ----------------
__global__ void __launch_bounds__(256) norm_bf16_kernel(const float* __restrict__ e,
                                                        unsigned int* __restrict__ en_packed) {
    const int row  = blockIdx.x * 4 + (threadIdx.x >> 6);  // one wave per row
    const int lane = threadIdx.x & 63;
    const float2 v = *reinterpret_cast<const float2*>(e + row * DIM + lane * 2);
    float s = v.x * v.x + v.y * v.y;
    #pragma unroll
    for (int off = 32; off; off >>= 1) s += __shfl_xor(s, off, 64);
    const float scale = 1.0f / fmaxf(sqrtf(s), 1e-8f);
    const unsigned int lo = f2bf(v.x * scale);
    const unsigned int hi = f2bf(v.y * scale);
    en_packed[row * (DIM / 2) + lane] = (hi << 16) | lo;
}

// ---------------- K2: strip-chunked tile GEMM + fused hinge loss ----------------
__global__ void __launch_bounds__(256, 2)
tri_loss_kernel(const short* __restrict__ en, const int* __restrict__ labels,
                float* __restrict__ partials, int nt) {
    __shared__ __align__(16) short Blds[2][128 * DIM];   // 2 x 32 KB double buffer
    __shared__ float wsum[4];

    const int bi    = blockIdx.y;                    // row-strip tile index
    const int jbase = bi + blockIdx.x * CHUNK;       // first col tile of this chunk
    const int bid   = blockIdx.y * gridDim.x + blockIdx.x;
    if (jbase >= nt) {                               // dead chunk
        if (threadIdx.x == 0) partials[bid] = 0.0f;
        return;
    }
    const int ntile = min(CHUNK, nt - jbase);

    const int tid  = threadIdx.x;
    const int lane = tid & 63;
    const int wid  = tid >> 6;           // 4 waves: 2x2 quadrants of the 128x128 tile
    const int wr   = wid >> 1, wc = wid & 1;
    const int lm   = lane & 15;
    const int hi   = lane >> 4;          // 0..3 (k-slot group)

    // ---- prologue: stage B tile 0 into buf 0 (pre-swizzled source) ----
    {
        const char* src = (const char*)(en + (size_t)jbase * 128 * DIM);
        char* dst = (char*)&Blds[0][0];
        #pragma unroll
        for (int r = 0; r < 8; ++r) {
            const int rl = r * 16 + wid * 4 + hi;          // lds-local row (0..127)
            const int sc = (lm ^ (rl & 7)) << 4;           // swizzled source col byte
            load16_to_lds(src + (size_t)rl * 256 + sc, dst + (r * 16 + wid * 4) * 256);
        }
    }

    // ---- A fragments in registers: this wave's 64-row half, full K=128 ----
    const int r0 = bi * 128 + wr * 64;
    short8 a[4][4];
    #pragma unroll
    for (int m = 0; m < 4; ++m) {
        const short* pa = en + (size_t)(r0 + m * 16 + lm) * DIM + hi * 8;
        #pragma unroll
        for (int ks = 0; ks < 4; ++ks)
            a[m][ks] = *(const short8*)(pa + ks * 32);
    }

    // ---- row labels: int4 per m (i = r0 + m*16 + rb + r) ----
    const int rb = hi * 4;
    int4 li[4];
    #pragma unroll
    for (int m = 0; m < 4; ++m)
        li[m] = *(const int4*)(labels + r0 + m * 16 + rb);

    float lsum = 0.0f;

    for (int t = 0; t < ntile; ++t) {
        const int bj  = jbase + t;
        const int cur = t & 1;
        __syncthreads();                 // buf[cur] staged & previous reads drained

        // issue stage of next tile into the other buffer (T3: stage BEFORE compute)
        if (t + 1 < ntile) {
            const char* src = (const char*)(en + (size_t)(bj + 1) * 128 * DIM);
            char* dst = (char*)&Blds[cur ^ 1][0];
            #pragma unroll
            for (int r = 0; r < 8; ++r) {
                const int rl = r * 16 + wid * 4 + hi;
                const int sc = (lm ^ (rl & 7)) << 4;
                load16_to_lds(src + (size_t)rl * 256 + sc, dst + (r * 16 + wid * 4) * 256);
            }
        }

        // B fragments from LDS (swizzled read; involution matches staging)
        const short8* Bv = (const short8*)&Blds[cur][0];
        short8 b[4][4];
        #pragma unroll
        for (int n = 0; n < 4; ++n) {
            const int jl = wc * 64 + n * 16 + lm;          // lds-local row of B
            #pragma unroll
            for (int ks = 0; ks < 4; ++ks) {
                const int slot = (ks * 4 + hi) ^ (jl & 7); // 16B-slot index 0..15
                b[n][ks] = Bv[jl * 16 + slot];
            }
        }

        f32x4 acc[4][4] = {};
        #pragma unroll
        for (int ks = 0; ks < 4; ++ks)
            #pragma unroll
            for (int m = 0; m < 4; ++m)
                #pragma unroll
                for (int n = 0; n < 4; ++n)
                    acc[m][n] = __builtin_amdgcn_mfma_f32_16x16x32_bf16(a[m][ks], b[n][ks], acc[m][n], 0, 0, 0);

        // ---- fused hinge epilogue (C/D map: col = lane&15, row = hi*4 + reg) ----
        const int c0 = bj * 128 + wc * 64;
        int labj[4];
        #pragma unroll
        for (int n = 0; n < 4; ++n) labj[n] = labels[c0 + n * 16 + lm];

        if (bj == bi) {  // diagonal tile: strict upper-triangle mask
            #pragma unroll
            for (int m = 0; m < 4; ++m) {
                #pragma unroll
                for (int r = 0; r < 4; ++r) {
                    const int i   = r0 + m * 16 + rb + r;
                    const int l_i = ((const int*)&li[m])[r];
                    #pragma unroll
                    for (int n = 0; n < 4; ++n) {
                        const int j = c0 + n * 16 + lm;
                        const float s  = acc[m][n][r];
                        const float t2 = (l_i == labj[n]) ? (1.0f - s) : (s - MARGIN);
                        if (i < j) lsum += fmaxf(t2, 0.0f);
                    }
                }
            }
        } else {         // strictly off-diagonal: every element counts
            #pragma unroll
            for (int m = 0; m < 4; ++m) {
                #pragma unroll
                for (int r = 0; r < 4; ++r) {
                    const int l_i = ((const int*)&li[m])[r];
                    #pragma unroll
                    for (int n = 0; n < 4; ++n) {
                        const float s  = acc[m][n][r];
                        const float t2 = (l_i == labj[n]) ? (1.0f - s) : (s - MARGIN);
                        lsum += fmaxf(t2, 0.0f);
                    }
                }
            }
        }
    }

    #pragma unroll
    for (int off = 32; off; off >>= 1) lsum += __shfl_down(lsum, off, 64);
    if (lane == 0) wsum[wid] = lsum;
    __syncthreads();
    if (tid == 0) partials[bid] = wsum[0] + wsum[1] + wsum[2] + wsum[3];
}

// ---------------- K3: final deterministic reduce ----------------
__global__ void __launch_bounds__(256) final_reduce_kernel(const float* __restrict__ partials,
                                                           float* __restrict__ out,
                                                           int n, float inv_denom) {
    float s = 0.0f;
    for (int i = threadIdx.x; i < n; i += 256) s += partials[i];
    #pragma unroll
    for (int off = 32; off; off >>= 1) s += __shfl_xor(s, off, 64);
    __shared__ float wsum[4];
    if ((threadIdx.x & 63) == 0) wsum[threadIdx.x >> 6] = s;
    __syncthreads();
    if (threadIdx.x == 0) out[0] = (wsum[0] + wsum[1] + wsum[2] + wsum[3]) * inv_denom;
}

extern "C" void kernel_launch(void* const* d_in, const int* in_sizes, int n_in,
                              void* d_out, int out_size, void* d_ws, size_t ws_size,
                              hipStream_t stream) {
    const float* emb    = (const float*)d_in[0];
    const int*   labels = (const int*)d_in[1];
    float*       out    = (float*)d_out;

    const int n  = in_sizes[1];              // 8192
    const int nt = n / 128;                  // 64 tiles per dim
    const int gx = (nt + CHUNK - 1) / CHUNK; // 16 chunks per strip

    unsigned int* en_packed = (unsigned int*)d_ws;                 // n*DIM bf16 = 2 MB
    short*        en        = (short*)d_ws;
    float*        partials  = (float*)((char*)d_ws + (size_t)n * DIM * 2);  // gx*nt floats

    norm_bf16_kernel<<<n / 4, 256, 0, stream>>>(emb, en_packed);

    dim3 grid2(gx, nt);
    tri_loss_kernel<<<grid2, 256, 0, stream>>>(en, labels, partials, nt);

    const float inv_denom = (float)(1.0 / ((double)n * (double)(n - 1)));
    final_reduce_kernel<<<1, 256, 0, stream>>>(partials, out, gx * nt, inv_denom);
}